// Round 9
// baseline (235.923 us; speedup 1.0000x reference)
//
#include <hip/hip_runtime.h>
#include <hip/hip_bf16.h>
#include <cstddef>
#include <cstdint>

#define NROWS 8192
#define LOG2E 1.4426950408889634f

typedef __attribute__((ext_vector_type(8))) short bf16x8;
typedef __attribute__((ext_vector_type(4))) float f32x4;

#define EXP2(x) __builtin_amdgcn_exp2f(x)

__device__ __forceinline__ short f2bf(float f) {
  unsigned u = __float_as_uint(f);
  u += 0x7fffu + ((u >> 16) & 1u);   // RNE
  return (short)(u >> 16);
}
__device__ __forceinline__ float leaky_f(float v) { return fmaxf(v, 0.1f * v); }

union BFPair { __hip_bfloat162 h; unsigned u; };
__device__ __forceinline__ unsigned pack2(float a, float b) {
  BFPair p;
  p.h = __float22bfloat162_rn(make_float2(a, b));  // v_cvt_pk_bf16_f32
  return p.u;
}

// ---------------- Kernel 1: MLP encoder: x[8192,256] -> x2, s(prescaled), sq, x2bfT --
extern "C" __global__ void __launch_bounds__(256)
encoder_kernel(const float* __restrict__ x, const float* __restrict__ W10,
               const float* __restrict__ b10, const float* __restrict__ W11,
               const float* __restrict__ b11, const float* __restrict__ avec,
               float* __restrict__ x2, float* __restrict__ sarr,
               float* __restrict__ sqarr, short* __restrict__ x2bfT) {
  __shared__ float xr[4][256];
  __shared__ float h1[4][128];
  const int t = threadIdx.x;
  const int r0 = blockIdx.x * 4;
#pragma unroll
  for (int r = 0; r < 4; ++r) xr[r][t] = x[(size_t)(r0 + r) * 256 + t];
  __syncthreads();
  if (t < 128) {
    float acc[4];
    const float b = b10[t];
#pragma unroll
    for (int r = 0; r < 4; ++r) acc[r] = b;
    const float* wrow = W10 + t * 256;
    for (int c = 0; c < 256; c += 4) {
      const float4 wv = *(const float4*)(wrow + c);
#pragma unroll
      for (int r = 0; r < 4; ++r) {
        acc[r] = fmaf(wv.x, xr[r][c], acc[r]);
        acc[r] = fmaf(wv.y, xr[r][c + 1], acc[r]);
        acc[r] = fmaf(wv.z, xr[r][c + 2], acc[r]);
        acc[r] = fmaf(wv.w, xr[r][c + 3], acc[r]);
      }
    }
#pragma unroll
    for (int r = 0; r < 4; ++r) h1[r][t] = leaky_f(acc[r]);
  }
  __syncthreads();
  if (t < 64) {
    float acc[4];
    const float b = b11[t];
#pragma unroll
    for (int r = 0; r < 4; ++r) acc[r] = b;
    const float* wrow = W11 + t * 128;
    for (int c = 0; c < 128; c += 4) {
      const float4 wv = *(const float4*)(wrow + c);
#pragma unroll
      for (int r = 0; r < 4; ++r) {
        acc[r] = fmaf(wv.x, h1[r][c], acc[r]);
        acc[r] = fmaf(wv.y, h1[r][c + 1], acc[r]);
        acc[r] = fmaf(wv.z, h1[r][c + 2], acc[r]);
        acc[r] = fmaf(wv.w, h1[r][c + 3], acc[r]);
      }
    }
    const float av = avec[t];
#pragma unroll
    for (int r = 0; r < 4; ++r) {
      const float v = leaky_f(acc[r]);
      x2[(size_t)(r0 + r) * 64 + t] = v;
      x2bfT[(size_t)t * NROWS + r0 + r] = f2bf(v);
      float ps = v * av, pq = v * v;
#pragma unroll
      for (int off = 1; off < 64; off <<= 1) {
        ps += __shfl_xor(ps, off);
        pq += __shfl_xor(pq, off);
      }
      if (t == 0) {
        sarr[r0 + r] = ps * LOG2E;          // exp(leaky(d)) = exp2(leaky(d*log2e))
        sqarr[r0 + r] = pq * (1.0f / 64.0f);
      }
    }
  }
}

// ---------------- Kernel 1b: B fragments for 16x16x32 MFMA (contiguous) -------------
// Bfrag[S][nf][lane][8]: x2^T[n = nf*16 + (lane&15)][k = S*32 + (lane>>4)*8 + e]
extern "C" __global__ void __launch_bounds__(256)
prep16_kernel(const short* __restrict__ x2bfT, short* __restrict__ Bfrag) {
  const int S = blockIdx.x;           // 256 groups of k=32
  const int t = threadIdx.x;
  const int nf = t >> 6, l = t & 63;
  const bf16x8 v = *(const bf16x8*)(x2bfT + (size_t)(nf * 16 + (l & 15)) * NROWS
                                    + S * 32 + (l >> 4) * 8);
  *(bf16x8*)(Bfrag + ((size_t)S * 4 + nf) * 512 + l * 8) = v;
}

// ---------------- Kernel 2a: compress A (rows 0..4095), LINEAR reads + LDS transpose -
// Block = [16 rows][512 cols]: wave w owns rows 4w..4w+3, reads each row as two
// 1KB fully-contiguous dwordx4 instructions. exp2 in regs, bf16 into LDS, then
// fragment-ordered contiguous 1KB writes to rawfrag. Exact fp32 row scalars.
extern "C" __global__ void __launch_bounds__(256, 6)
convA_lin(const float* __restrict__ A, const float* __restrict__ sarr,
          const float* __restrict__ sqarr, short* __restrict__ rawfrag,
          float* __restrict__ rsp, float* __restrict__ ssp, float* __restrict__ wsp) {
  __shared__ __attribute__((aligned(16))) short lraw[16][520];   // 1040B row stride
  const int t = threadIdx.x, l = t & 63, w = t >> 6;
  const int rt = blockIdx.x >> 4, jp = blockIdx.x & 15;
  const int jb = jp * 512;

  float prs[4] = {0.f,0.f,0.f,0.f}, pss[4] = {0.f,0.f,0.f,0.f}, pws[4] = {0.f,0.f,0.f,0.f};

#pragma unroll
  for (int q = 0; q < 4; ++q) {
    const int row = w * 4 + q;
    const int grow = rt * 16 + row;
    const float sif = sarr[grow];
    const float* ap = A + (size_t)grow * NROWS + jb;
#pragma unroll
    for (int h = 0; h < 2; ++h) {
      const f32x4 a4 = *(const f32x4*)(ap + h * 256 + l * 4);
      const f32x4 sj = *(const f32x4*)(sarr + jb + h * 256 + l * 4);
      const f32x4 sq = *(const f32x4*)(sqarr + jb + h * 256 + l * 4);
      const float d0 = sif - sj[0], d1 = sif - sj[1];
      const float d2 = sif - sj[2], d3 = sif - sj[3];
      const float r0 = EXP2(fmaxf(d0, 0.1f * d0)) * a4[0];
      const float r1 = EXP2(fmaxf(d1, 0.1f * d1)) * a4[1];
      const float r2 = EXP2(fmaxf(d2, 0.1f * d2)) * a4[2];
      const float r3 = EXP2(fmaxf(d3, 0.1f * d3)) * a4[3];
      prs[q] += (r0 + r1) + (r2 + r3);
      pss[q] = fmaf(r0, r0, pss[q]); pss[q] = fmaf(r1, r1, pss[q]);
      pss[q] = fmaf(r2, r2, pss[q]); pss[q] = fmaf(r3, r3, pss[q]);
      pws[q] = fmaf(r0, sq[0], pws[q]); pws[q] = fmaf(r1, sq[1], pws[q]);
      pws[q] = fmaf(r2, sq[2], pws[q]); pws[q] = fmaf(r3, sq[3], pws[q]);
      uint2 pk;
      pk.x = pack2(r0, r1);
      pk.y = pack2(r2, r3);
      *(uint2*)((char*)lraw + row * 1040 + h * 512 + l * 8) = pk;
    }
  }
  __syncthreads();
  // fragment phase: wave w writes S-tiles 4w..4w+3, 1KB contiguous each
#pragma unroll
  for (int q = 0; q < 4; ++q) {
    const int S = w * 4 + q;
    const bf16x8 fr = *(const bf16x8*)((const char*)lraw + (l & 15) * 1040
                                       + S * 64 + (l >> 4) * 16);
    *(bf16x8*)(rawfrag + (((size_t)rt * 256 + jp * 16 + S) * 64 + l) * 8) = fr;
  }
  // per-row scalar reduce (full wave) + write
#pragma unroll
  for (int q = 0; q < 4; ++q) {
    float a = prs[q], b = pss[q], c = pws[q];
#pragma unroll
    for (int off = 1; off < 64; off <<= 1) {
      a += __shfl_xor(a, off);
      b += __shfl_xor(b, off);
      c += __shfl_xor(c, off);
    }
    if (l == 0) {
      const int grow = rt * 16 + w * 4 + q;
      rsp[jp * NROWS + grow] = a;
      ssp[jp * NROWS + grow] = b;
      wsp[jp * NROWS + grow] = c;
    }
  }
}

// ---------------- Kernel 2b: compress A (rows 4096..8191), fragment-SCATTER reads ----
// No LDS transpose: lane l reads A[rt*16 + (l&15)][S*32 + (l>>4)*8 ..+8) directly
// (two dwordx4, 16 row-segments per instr), writes the fragment contiguously.
extern "C" __global__ void __launch_bounds__(256, 6)
convA_frag(const float* __restrict__ A, const float* __restrict__ sarr,
           const float* __restrict__ sqarr, short* __restrict__ rawfrag,
           float* __restrict__ rsp, float* __restrict__ ssp, float* __restrict__ wsp) {
  __shared__ float red[4][48];
  const int t = threadIdx.x, l = t & 63, w = t >> 6;
  const int rt = 256 + (blockIdx.x >> 4), jp = blockIdx.x & 15;
  const int jb = jp * 512;
  const int row = rt * 16 + (l & 15);
  const int kg = l >> 4;
  const float sif = sarr[row];
  const float* ap  = A + (size_t)row * NROWS + jb + kg * 8;
  const float* sjp = sarr + jb + kg * 8;
  const float* sqp = sqarr + jb + kg * 8;

  float prs = 0.f, pss = 0.f, pws = 0.f;
#pragma unroll
  for (int q = 0; q < 4; ++q) {
    const int S = w * 4 + q;
    const f32x4 a0 = *(const f32x4*)(ap + S * 32);
    const f32x4 a1 = *(const f32x4*)(ap + S * 32 + 4);
    const f32x4 s0 = *(const f32x4*)(sjp + S * 32);
    const f32x4 s1 = *(const f32x4*)(sjp + S * 32 + 4);
    const f32x4 q0 = *(const f32x4*)(sqp + S * 32);
    const f32x4 q1 = *(const f32x4*)(sqp + S * 32 + 4);
    const float d0 = sif - s0[0], d1 = sif - s0[1], d2 = sif - s0[2], d3 = sif - s0[3];
    const float d4 = sif - s1[0], d5 = sif - s1[1], d6 = sif - s1[2], d7 = sif - s1[3];
    const float r0 = EXP2(fmaxf(d0, 0.1f * d0)) * a0[0];
    const float r1 = EXP2(fmaxf(d1, 0.1f * d1)) * a0[1];
    const float r2 = EXP2(fmaxf(d2, 0.1f * d2)) * a0[2];
    const float r3 = EXP2(fmaxf(d3, 0.1f * d3)) * a0[3];
    const float r4 = EXP2(fmaxf(d4, 0.1f * d4)) * a1[0];
    const float r5 = EXP2(fmaxf(d5, 0.1f * d5)) * a1[1];
    const float r6 = EXP2(fmaxf(d6, 0.1f * d6)) * a1[2];
    const float r7 = EXP2(fmaxf(d7, 0.1f * d7)) * a1[3];
    prs += ((r0 + r1) + (r2 + r3)) + ((r4 + r5) + (r6 + r7));
    pss = fmaf(r0, r0, pss); pss = fmaf(r1, r1, pss);
    pss = fmaf(r2, r2, pss); pss = fmaf(r3, r3, pss);
    pss = fmaf(r4, r4, pss); pss = fmaf(r5, r5, pss);
    pss = fmaf(r6, r6, pss); pss = fmaf(r7, r7, pss);
    pws = fmaf(r0, q0[0], pws); pws = fmaf(r1, q0[1], pws);
    pws = fmaf(r2, q0[2], pws); pws = fmaf(r3, q0[3], pws);
    pws = fmaf(r4, q1[0], pws); pws = fmaf(r5, q1[1], pws);
    pws = fmaf(r6, q1[2], pws); pws = fmaf(r7, q1[3], pws);
    union { bf16x8 v; unsigned u[4]; } pk;
    pk.u[0] = pack2(r0, r1); pk.u[1] = pack2(r2, r3);
    pk.u[2] = pack2(r4, r5); pk.u[3] = pack2(r6, r7);
    *(bf16x8*)(rawfrag + (((size_t)rt * 256 + jp * 16 + S) * 64 + l) * 8) = pk.v;
  }
  // reduce across the 4 lanes sharing a row, then across waves via LDS
  prs += __shfl_xor(prs, 16); prs += __shfl_xor(prs, 32);
  pss += __shfl_xor(pss, 16); pss += __shfl_xor(pss, 32);
  pws += __shfl_xor(pws, 16); pws += __shfl_xor(pws, 32);
  if (l < 16) { red[w][l] = prs; red[w][16 + l] = pss; red[w][32 + l] = pws; }
  __syncthreads();
  if (w == 0 && l < 16) {
    const int grow = rt * 16 + l;
    rsp[jp * NROWS + grow] = red[0][l] + red[1][l] + red[2][l] + red[3][l];
    ssp[jp * NROWS + grow] = red[0][16 + l] + red[1][16 + l] + red[2][16 + l] + red[3][16 + l];
    wsp[jp * NROWS + grow] = red[0][32 + l] + red[1][32 + l] + red[2][32 + l] + red[3][32 + l];
  }
}

// ---------------- Kernel 3: GEMM over fragment-ordered raw (L3-hot, linear) ---------
extern "C" __global__ void __launch_bounds__(256, 6)
gemm3(const short* __restrict__ rawfrag, const short* __restrict__ Bfrag,
      float* __restrict__ yp) {
  const int t = threadIdx.x, l = t & 63, w = t >> 6;
  const int rg = blockIdx.x >> 4, kp = blockIdx.x & 15;
  const int rt = rg * 4 + w;
  const short* ap = rawfrag + (((size_t)rt * 256 + kp * 16) * 64 + l) * 8;
  const short* bp = Bfrag + ((size_t)kp * 16 * 4) * 512 + l * 8;

  f32x4 acc0 = {0.f,0.f,0.f,0.f}, acc1 = {0.f,0.f,0.f,0.f};
  f32x4 acc2 = {0.f,0.f,0.f,0.f}, acc3 = {0.f,0.f,0.f,0.f};
#pragma unroll
  for (int s = 0; s < 16; ++s) {
    const bf16x8 ar = *(const bf16x8*)(ap + s * 512);
    const bf16x8 b0 = *(const bf16x8*)(bp + (s * 4 + 0) * 512);
    const bf16x8 b1 = *(const bf16x8*)(bp + (s * 4 + 1) * 512);
    const bf16x8 b2 = *(const bf16x8*)(bp + (s * 4 + 2) * 512);
    const bf16x8 b3 = *(const bf16x8*)(bp + (s * 4 + 3) * 512);
    acc0 = __builtin_amdgcn_mfma_f32_16x16x32_bf16(ar, b0, acc0, 0, 0, 0);
    acc1 = __builtin_amdgcn_mfma_f32_16x16x32_bf16(ar, b1, acc1, 0, 0, 0);
    acc2 = __builtin_amdgcn_mfma_f32_16x16x32_bf16(ar, b2, acc2, 0, 0, 0);
    acc3 = __builtin_amdgcn_mfma_f32_16x16x32_bf16(ar, b3, acc3, 0, 0, 0);
  }
  float* ypb = yp + (size_t)kp * NROWS * 64;
  const f32x4 accs[4] = {acc0, acc1, acc2, acc3};
#pragma unroll
  for (int nf = 0; nf < 4; ++nf)
#pragma unroll
    for (int ri = 0; ri < 4; ++ri)
      ypb[(size_t)(rt * 16 + (l >> 4) * 4 + ri) * 64 + nf * 16 + (l & 15)] = accs[nf][ri];
}

// ---------------- Kernel 4: combine partials, GNN layer + head, per-row losses ------
extern "C" __global__ void __launch_bounds__(256)
finish_kernel(const float* __restrict__ x2, const float* __restrict__ sqarr,
              const float* __restrict__ yp, const float* __restrict__ rsp,
              const float* __restrict__ ssp, const float* __restrict__ wsp,
              const float* __restrict__ Wg, const float* __restrict__ bg,
              const float* __restrict__ W2, const float* __restrict__ b2,
              float* __restrict__ outp, float* __restrict__ l1c, float* __restrict__ l2c) {
  __shared__ float hbuf[4][64];
  __shared__ float gbuf[4][64];
  const int t = threadIdx.x;
  const int w = t >> 6, lane = t & 63;
  const int i = blockIdx.x * 4 + w;

  float yv = 0.f, rowsum = 0.f, sumsq = 0.f, wsq = 0.f;
#pragma unroll
  for (int p = 0; p < 16; ++p) {
    yv += yp[(size_t)p * NROWS * 64 + (size_t)i * 64 + lane];
    rowsum += rsp[p * NROWS + i];
    sumsq += ssp[p * NROWS + i];
    wsq += wsp[p * NROWS + i];
  }
  const float inv = 1.0f / rowsum;
  hbuf[w][lane] = yv * inv;
  const float xv = x2[(size_t)i * 64 + lane];
  float xy = xv * yv;
#pragma unroll
  for (int off = 1; off < 64; off <<= 1) xy += __shfl_xor(xy, off);
  if (lane == 0) {
    l1c[i] = sqarr[i] + (wsq - (2.0f / 64.0f) * xy) * inv;
    l2c[i] = sumsq * inv * inv;
  }
  __syncthreads();
  float accg = bg[lane];
  {
    const float* wrow = Wg + lane * 64;
#pragma unroll 4
    for (int d = 0; d < 64; ++d) accg = fmaf(wrow[d], hbuf[w][d], accg);
  }
  gbuf[w][lane] = leaky_f(accg);
  __syncthreads();
  if (lane < 32) {
    float acco = b2[lane];
    const float* wrow = W2 + lane * 64;
#pragma unroll 4
    for (int d = 0; d < 64; ++d) acco = fmaf(wrow[d], gbuf[w][d], acco);
    outp[(size_t)i * 32 + lane] = acco;
  }
}

// ---------------- Kernel 5: scalar loss reduction -----------------------------------
extern "C" __global__ void __launch_bounds__(256)
loss_kernel(const float* __restrict__ l1c, const float* __restrict__ l2c,
            float* __restrict__ outp) {
  __shared__ float s1[256], s2[256];
  const int t = threadIdx.x;
  float a1 = 0.f, a2 = 0.f;
  for (int i = t * 4; i < NROWS; i += 1024) {
    const float4 v1 = *(const float4*)(l1c + i);
    const float4 v2 = *(const float4*)(l2c + i);
    a1 += (v1.x + v1.y) + (v1.z + v1.w);
    a2 += (v2.x + v2.y) + (v2.z + v2.w);
  }
  s1[t] = a1; s2[t] = a2;
  __syncthreads();
  for (int off = 128; off > 0; off >>= 1) {
    if (t < off) { s1[t] += s1[t + off]; s2[t] += s2[t + off]; }
    __syncthreads();
  }
  if (t == 0) {
    const float scale = 1.0f / ((float)NROWS * (float)NROWS);
    outp[NROWS * 32] = s1[0] * scale;
    outp[NROWS * 32 + 1] = s2[0] * scale;
  }
}

// ---------------- launch ------------------------------------------------------------
extern "C" void kernel_launch(void* const* d_in, const int* in_sizes, int n_in,
                              void* d_out, int out_size, void* d_ws, size_t ws_size,
                              hipStream_t stream) {
  const float* x   = (const float*)d_in[0];
  const float* A   = (const float*)d_in[1];
  const float* W10 = (const float*)d_in[2];
  const float* b10 = (const float*)d_in[3];
  const float* W11 = (const float*)d_in[4];
  const float* b11 = (const float*)d_in[5];
  const float* av  = (const float*)d_in[6];
  const float* Wg  = (const float*)d_in[7];
  const float* bg  = (const float*)d_in[8];
  const float* W2  = (const float*)d_in[9];
  const float* b2  = (const float*)d_in[10];
  float* out = (float*)d_out;

  // workspace layout (~174 MB; ws is 1 GiB per harness poison evidence)
  float* ws    = (float*)d_ws;
  float* x2    = ws;                                  // N*64
  float* sarr  = x2 + (size_t)NROWS * 64;             // N (prescaled by log2e)
  float* sqarr = sarr + NROWS;                        // N
  float* l1c   = sqarr + NROWS;                       // N
  float* l2c   = l1c + NROWS;                         // N
  float* rsp   = l2c + NROWS;                         // 16*N
  float* ssp   = rsp + (size_t)16 * NROWS;            // 16*N
  float* wsp   = ssp + (size_t)16 * NROWS;            // 16*N
  float* yp    = wsp + (size_t)16 * NROWS;            // 16*N*64
  short* x2bfT = (short*)(yp + (size_t)16 * NROWS * 64);   // N*64 bf16
  short* Bfrag = x2bfT + (size_t)NROWS * 64;          // 256*4*512 bf16 (1MB)
  short* rawfrag = Bfrag + (size_t)256 * 2048;        // 512*256*512 bf16 (134MB)

  hipLaunchKernelGGL(encoder_kernel, dim3(2048), dim3(256), 0, stream,
                     x, W10, b10, W11, b11, av, x2, sarr, sqarr, x2bfT);
  hipLaunchKernelGGL(prep16_kernel, dim3(256), dim3(256), 0, stream, x2bfT, Bfrag);
  hipLaunchKernelGGL(convA_lin, dim3(4096), dim3(256), 0, stream,
                     A, sarr, sqarr, rawfrag, rsp, ssp, wsp);
  hipLaunchKernelGGL(convA_frag, dim3(4096), dim3(256), 0, stream,
                     A, sarr, sqarr, rawfrag, rsp, ssp, wsp);
  hipLaunchKernelGGL(gemm3, dim3(2048), dim3(256), 0, stream, rawfrag, Bfrag, yp);
  hipLaunchKernelGGL(finish_kernel, dim3(2048), dim3(256), 0, stream,
                     x2, sqarr, yp, rsp, ssp, wsp, Wg, bg, W2, b2, out, l1c, l2c);
  hipLaunchKernelGGL(loss_kernel, dim3(1), dim3(256), 0, stream, l1c, l2c, out);
}

// Round 10
// 187.074 us; speedup vs baseline: 1.2611x; 1.2611x over previous
//
#include <hip/hip_runtime.h>
#include <hip/hip_bf16.h>
#include <cstddef>
#include <cstdint>

#define NROWS 8192
#define LOG2E 1.4426950408889634f

typedef __attribute__((ext_vector_type(8))) short bf16x8;
typedef __attribute__((ext_vector_type(4))) float f32x4;

#define EXP2(x) __builtin_amdgcn_exp2f(x)

__device__ __forceinline__ short f2bf(float f) {
  unsigned u = __float_as_uint(f);
  u += 0x7fffu + ((u >> 16) & 1u);   // RNE
  return (short)(u >> 16);
}
__device__ __forceinline__ float leaky_f(float v) { return fmaxf(v, 0.1f * v); }

union BFPair { __hip_bfloat162 h; unsigned u; };
__device__ __forceinline__ unsigned pack2(float a, float b) {
  BFPair p;
  p.h = __float22bfloat162_rn(make_float2(a, b));  // v_cvt_pk_bf16_f32
  return p.u;
}

__device__ __forceinline__ f32x4 ntload4(const float* p) {
  return __builtin_nontemporal_load((const f32x4*)p);   // global_load_dwordx4 ... nt
}

// ---------------- Kernel 1: MLP encoder: x[8192,256] -> x2, s(prescaled), sq, x2bfT --
extern "C" __global__ void __launch_bounds__(256)
encoder_kernel(const float* __restrict__ x, const float* __restrict__ W10,
               const float* __restrict__ b10, const float* __restrict__ W11,
               const float* __restrict__ b11, const float* __restrict__ avec,
               float* __restrict__ x2, float* __restrict__ sarr,
               float* __restrict__ sqarr, short* __restrict__ x2bfT) {
  __shared__ float xr[4][256];
  __shared__ float h1[4][128];
  const int t = threadIdx.x;
  const int r0 = blockIdx.x * 4;
#pragma unroll
  for (int r = 0; r < 4; ++r) xr[r][t] = x[(size_t)(r0 + r) * 256 + t];
  __syncthreads();
  if (t < 128) {
    float acc[4];
    const float b = b10[t];
#pragma unroll
    for (int r = 0; r < 4; ++r) acc[r] = b;
    const float* wrow = W10 + t * 256;
    for (int c = 0; c < 256; c += 4) {
      const float4 wv = *(const float4*)(wrow + c);
#pragma unroll
      for (int r = 0; r < 4; ++r) {
        acc[r] = fmaf(wv.x, xr[r][c], acc[r]);
        acc[r] = fmaf(wv.y, xr[r][c + 1], acc[r]);
        acc[r] = fmaf(wv.z, xr[r][c + 2], acc[r]);
        acc[r] = fmaf(wv.w, xr[r][c + 3], acc[r]);
      }
    }
#pragma unroll
    for (int r = 0; r < 4; ++r) h1[r][t] = leaky_f(acc[r]);
  }
  __syncthreads();
  if (t < 64) {
    float acc[4];
    const float b = b11[t];
#pragma unroll
    for (int r = 0; r < 4; ++r) acc[r] = b;
    const float* wrow = W11 + t * 128;
    for (int c = 0; c < 128; c += 4) {
      const float4 wv = *(const float4*)(wrow + c);
#pragma unroll
      for (int r = 0; r < 4; ++r) {
        acc[r] = fmaf(wv.x, h1[r][c], acc[r]);
        acc[r] = fmaf(wv.y, h1[r][c + 1], acc[r]);
        acc[r] = fmaf(wv.z, h1[r][c + 2], acc[r]);
        acc[r] = fmaf(wv.w, h1[r][c + 3], acc[r]);
      }
    }
    const float av = avec[t];
#pragma unroll
    for (int r = 0; r < 4; ++r) {
      const float v = leaky_f(acc[r]);
      x2[(size_t)(r0 + r) * 64 + t] = v;
      x2bfT[(size_t)t * NROWS + r0 + r] = f2bf(v);
      float ps = v * av, pq = v * v;
#pragma unroll
      for (int off = 1; off < 64; off <<= 1) {
        ps += __shfl_xor(ps, off);
        pq += __shfl_xor(pq, off);
      }
      if (t == 0) {
        sarr[r0 + r] = ps * LOG2E;          // exp(leaky(d)) = exp2(leaky(d*log2e))
        sqarr[r0 + r] = pq * (1.0f / 64.0f);
      }
    }
  }
}

// ---------------- Kernel 1b: B + Ext fragments (16x16x32 layout, contiguous) --------
// Bfrag[S][nf][lane][8]: x2^T[n = nf*16 + (lane&15)][k = S*32 + (lane>>4)*8 + e]
// Ext[S][lane][8]: col0 = 1.0 (rowsum), col1 = sq_k (wsq), else 0
extern "C" __global__ void __launch_bounds__(256)
prep_kernel(const short* __restrict__ x2bfT, const float* __restrict__ sqarr,
            short* __restrict__ Bfrag, short* __restrict__ Ext) {
  const int S = blockIdx.x;           // 256 k-groups of 32
  const int t = threadIdx.x;
  const int nf = t >> 6, l = t & 63;
  const int fr = l & 15, kg = l >> 4;
  const bf16x8 v = *(const bf16x8*)(x2bfT + (size_t)(nf * 16 + fr) * NROWS + S * 32 + kg * 8);
  *(bf16x8*)(Bfrag + ((size_t)S * 4 + nf) * 512 + l * 8) = v;
  if (nf == 0) {
    bf16x8 e;
    if (fr == 0) {
#pragma unroll
      for (int i = 0; i < 8; ++i) e[i] = (short)0x3F80;      // bf16 1.0
    } else if (fr == 1) {
#pragma unroll
      for (int i = 0; i < 8; ++i) e[i] = f2bf(sqarr[S * 32 + kg * 8 + i]);
    } else {
#pragma unroll
      for (int i = 0; i < 8; ++i) e[i] = 0;
    }
    *(bf16x8*)(Ext + (size_t)S * 512 + l * 8) = e;
  }
}

// ---------------- Kernel 2: single fused A-pass, nt loads, high TLP -----------------
// Grid 1024 (128 rowgroups x 8 jsplit), 4 blocks/CU, 16 waves/CU. Wave owns 16 rows.
// Per 256-col chunk: E = 16 linear 1KB row-loads (NON-TEMPORAL, compiler-scheduled),
// exp2 in regs, pack bf16 into wave-private LDS fragments; M = 8 k-steps of
// {linear ds_read_b128 A-frag + 5 L2-hot frag loads + 6 MFMA}. One barrier total.
// rowsum/wsq via Ext MFMA column trick; sumsq via mfma(raw,raw) diagonal.
extern "C" __global__ void __launch_bounds__(256, 4)
fused16_kernel(const float* __restrict__ A, const float* __restrict__ sarr,
               const short* __restrict__ Bfrag, const short* __restrict__ Ext,
               float* __restrict__ yp, float* __restrict__ rsp,
               float* __restrict__ ssp, float* __restrict__ wsp) {
  // per-wave fragment buffer: 8 S-tiles x (1024B + 32B pad) = 8448 B
  __shared__ __attribute__((aligned(16))) char fragbuf[4][8448];
  __shared__ __attribute__((aligned(16))) float sjbuf[1024];
  __shared__ float sibuf[64];

  const int t = threadIdx.x;
  const int l = t & 63;
  const int w = __builtin_amdgcn_readfirstlane(t >> 6);
  const int fr = l & 15, kg = l >> 4;
  const int bi = blockIdx.x & 127;          // rowgroup
  const int js = blockIdx.x >> 7;           // 0..7
  const int i0 = bi * 64;
  const int jb = js * 1024;
  const int row0 = i0 + w * 16;

  for (int k = t; k < 1024; k += 256) sjbuf[k] = sarr[jb + k];
  if (t < 64) sibuf[t] = sarr[i0 + t];
  __syncthreads();   // the only barrier

  char* myf = fragbuf[w];
  // E-write address: lane l covers row r, cols l*4..l*4+3 of the chunk:
  //   S = l>>3, k-granule kg_w = (l&7)>>1, half = l&1
  const int ebase = (l >> 3) * 1056 + (((l & 7) >> 1) * 16) * 16 + (l & 1) * 8;

  f32x4 acc0 = {0.f,0.f,0.f,0.f}, acc1 = {0.f,0.f,0.f,0.f};
  f32x4 acc2 = {0.f,0.f,0.f,0.f}, acc3 = {0.f,0.f,0.f,0.f};
  f32x4 acce = {0.f,0.f,0.f,0.f}, accd = {0.f,0.f,0.f,0.f};

#pragma unroll 1
  for (int ch = 0; ch < 4; ++ch) {
    const float* ap = A + (size_t)row0 * NROWS + jb + ch * 256 + l * 4;
    const f32x4 sjv = *(const f32x4*)(sjbuf + ch * 256 + l * 4);

    // ---- phase E: 2 half-phases x 8 rows; each instruction = one 1KB linear run ----
#pragma unroll
    for (int h = 0; h < 2; ++h) {
      f32x4 av[8];
#pragma unroll
      for (int r = 0; r < 8; ++r) av[r] = ntload4(ap + (size_t)(h * 8 + r) * NROWS);
#pragma unroll
      for (int r = 0; r < 8; ++r) {
        const int row = h * 8 + r;
        const float sif = sibuf[w * 16 + row];
        const float d0 = sif - sjv[0], d1 = sif - sjv[1];
        const float d2 = sif - sjv[2], d3 = sif - sjv[3];
        const float e0 = EXP2(fmaxf(d0, 0.1f * d0)) * av[r][0];
        const float e1 = EXP2(fmaxf(d1, 0.1f * d1)) * av[r][1];
        const float e2 = EXP2(fmaxf(d2, 0.1f * d2)) * av[r][2];
        const float e3 = EXP2(fmaxf(d3, 0.1f * d3)) * av[r][3];
        uint2 pk;
        pk.x = pack2(e0, e1);
        pk.y = pack2(e2, e3);
        *(uint2*)(myf + ebase + row * 16) = pk;
      }
    }
    // wave-private LDS: order E-writes before M-reads (rule #18 fence)
    asm volatile("s_waitcnt lgkmcnt(0)" ::: "memory");
    __builtin_amdgcn_sched_barrier(0);

    // ---- phase M: 8 k-steps, linear A-frag reads + L2-hot B/Ext + 6 MFMA ----
    const int Sg0 = (jb + ch * 256) >> 5;
#pragma unroll
    for (int s = 0; s < 8; ++s) {
      const bf16x8 ar = *(const bf16x8*)(myf + s * 1056 + l * 16);
      const short* bp = Bfrag + (size_t)(Sg0 + s) * 2048 + l * 8;
      const bf16x8 b0 = *(const bf16x8*)(bp);
      const bf16x8 b1 = *(const bf16x8*)(bp + 512);
      const bf16x8 b2 = *(const bf16x8*)(bp + 1024);
      const bf16x8 b3 = *(const bf16x8*)(bp + 1536);
      const bf16x8 ef = *(const bf16x8*)(Ext + (size_t)(Sg0 + s) * 512 + l * 8);
      acc0 = __builtin_amdgcn_mfma_f32_16x16x32_bf16(ar, b0, acc0, 0, 0, 0);
      acc1 = __builtin_amdgcn_mfma_f32_16x16x32_bf16(ar, b1, acc1, 0, 0, 0);
      acc2 = __builtin_amdgcn_mfma_f32_16x16x32_bf16(ar, b2, acc2, 0, 0, 0);
      acc3 = __builtin_amdgcn_mfma_f32_16x16x32_bf16(ar, b3, acc3, 0, 0, 0);
      acce = __builtin_amdgcn_mfma_f32_16x16x32_bf16(ar, ef, acce, 0, 0, 0);
      accd = __builtin_amdgcn_mfma_f32_16x16x32_bf16(ar, ar, accd, 0, 0, 0);
    }
    // M-reads complete before next chunk's E-writes reuse the buffer
    asm volatile("s_waitcnt lgkmcnt(0)" ::: "memory");
    __builtin_amdgcn_sched_barrier(0);
  }

  // ---- epilogue: C/D layout col = lane&15, row = (lane>>4)*4 + reg ----
  float* ypb = yp + (size_t)js * NROWS * 64;
  const f32x4 accs[4] = {acc0, acc1, acc2, acc3};
#pragma unroll
  for (int nf = 0; nf < 4; ++nf)
#pragma unroll
    for (int ri = 0; ri < 4; ++ri)
      ypb[(size_t)(row0 + kg * 4 + ri) * 64 + nf * 16 + fr] = accs[nf][ri];
#pragma unroll
  for (int ri = 0; ri < 4; ++ri) {
    const int gi = row0 + kg * 4 + ri;
    if (fr == 0) rsp[js * NROWS + gi] = acce[ri];            // rowsum
    if (fr == 1) wsp[js * NROWS + gi] = acce[ri];            // wsq
    if (fr == kg * 4 + ri) ssp[js * NROWS + gi] = accd[ri];  // sumsq (diag)
  }
}

// ---------------- Kernel 3: combine partials, GNN layer + head, per-row losses ------
extern "C" __global__ void __launch_bounds__(256)
finish_kernel(const float* __restrict__ x2, const float* __restrict__ sqarr,
              const float* __restrict__ yp, const float* __restrict__ rsp,
              const float* __restrict__ ssp, const float* __restrict__ wsp,
              const float* __restrict__ Wg, const float* __restrict__ bg,
              const float* __restrict__ W2, const float* __restrict__ b2,
              float* __restrict__ outp, float* __restrict__ l1c, float* __restrict__ l2c) {
  __shared__ float hbuf[4][64];
  __shared__ float gbuf[4][64];
  const int t = threadIdx.x;
  const int w = t >> 6, lane = t & 63;
  const int i = blockIdx.x * 4 + w;

  float yv = 0.f, rowsum = 0.f, sumsq = 0.f, wsq = 0.f;
#pragma unroll
  for (int p = 0; p < 8; ++p) {
    yv += yp[(size_t)p * NROWS * 64 + (size_t)i * 64 + lane];
    rowsum += rsp[p * NROWS + i];
    sumsq += ssp[p * NROWS + i];
    wsq += wsp[p * NROWS + i];
  }
  const float inv = 1.0f / rowsum;
  hbuf[w][lane] = yv * inv;
  const float xv = x2[(size_t)i * 64 + lane];
  float xy = xv * yv;
#pragma unroll
  for (int off = 1; off < 64; off <<= 1) xy += __shfl_xor(xy, off);
  if (lane == 0) {
    l1c[i] = sqarr[i] + (wsq - (2.0f / 64.0f) * xy) * inv;
    l2c[i] = sumsq * inv * inv;
  }
  __syncthreads();
  float accg = bg[lane];
  {
    const float* wrow = Wg + lane * 64;
#pragma unroll 4
    for (int d = 0; d < 64; ++d) accg = fmaf(wrow[d], hbuf[w][d], accg);
  }
  gbuf[w][lane] = leaky_f(accg);
  __syncthreads();
  if (lane < 32) {
    float acco = b2[lane];
    const float* wrow = W2 + lane * 64;
#pragma unroll 4
    for (int d = 0; d < 64; ++d) acco = fmaf(wrow[d], gbuf[w][d], acco);
    outp[(size_t)i * 32 + lane] = acco;
  }
}

// ---------------- Kernel 4: scalar loss reduction -----------------------------------
extern "C" __global__ void __launch_bounds__(256)
loss_kernel(const float* __restrict__ l1c, const float* __restrict__ l2c,
            float* __restrict__ outp) {
  __shared__ float s1[256], s2[256];
  const int t = threadIdx.x;
  float a1 = 0.f, a2 = 0.f;
  for (int i = t * 4; i < NROWS; i += 1024) {
    const float4 v1 = *(const float4*)(l1c + i);
    const float4 v2 = *(const float4*)(l2c + i);
    a1 += (v1.x + v1.y) + (v1.z + v1.w);
    a2 += (v2.x + v2.y) + (v2.z + v2.w);
  }
  s1[t] = a1; s2[t] = a2;
  __syncthreads();
  for (int off = 128; off > 0; off >>= 1) {
    if (t < off) { s1[t] += s1[t + off]; s2[t] += s2[t + off]; }
    __syncthreads();
  }
  if (t == 0) {
    const float scale = 1.0f / ((float)NROWS * (float)NROWS);
    outp[NROWS * 32] = s1[0] * scale;
    outp[NROWS * 32 + 1] = s2[0] * scale;
  }
}

// ---------------- launch ------------------------------------------------------------
extern "C" void kernel_launch(void* const* d_in, const int* in_sizes, int n_in,
                              void* d_out, int out_size, void* d_ws, size_t ws_size,
                              hipStream_t stream) {
  const float* x   = (const float*)d_in[0];
  const float* A   = (const float*)d_in[1];
  const float* W10 = (const float*)d_in[2];
  const float* b10 = (const float*)d_in[3];
  const float* W11 = (const float*)d_in[4];
  const float* b11 = (const float*)d_in[5];
  const float* av  = (const float*)d_in[6];
  const float* Wg  = (const float*)d_in[7];
  const float* bg  = (const float*)d_in[8];
  const float* W2  = (const float*)d_in[9];
  const float* b2  = (const float*)d_in[10];
  float* out = (float*)d_out;

  // workspace layout (~22 MB)
  float* ws    = (float*)d_ws;
  float* x2    = ws;                                  // N*64
  float* sarr  = x2 + (size_t)NROWS * 64;             // N (prescaled by log2e)
  float* sqarr = sarr + NROWS;                        // N
  float* l1c   = sqarr + NROWS;                       // N
  float* l2c   = l1c + NROWS;                         // N
  float* rsp   = l2c + NROWS;                         // 8*N
  float* ssp   = rsp + (size_t)8 * NROWS;             // 8*N
  float* wsp   = ssp + (size_t)8 * NROWS;             // 8*N
  float* yp    = wsp + (size_t)8 * NROWS;             // 8*N*64
  short* x2bfT = (short*)(yp + (size_t)8 * NROWS * 64);   // N*64 bf16
  short* Bfrag = x2bfT + (size_t)NROWS * 64;          // 256*2048 bf16 (1MB)
  short* Ext   = Bfrag + (size_t)256 * 2048;          // 256*512 bf16 (256KB)

  hipLaunchKernelGGL(encoder_kernel, dim3(2048), dim3(256), 0, stream,
                     x, W10, b10, W11, b11, av, x2, sarr, sqarr, x2bfT);
  hipLaunchKernelGGL(prep_kernel, dim3(256), dim3(256), 0, stream,
                     x2bfT, sqarr, Bfrag, Ext);
  hipLaunchKernelGGL(fused16_kernel, dim3(1024), dim3(256), 0, stream,
                     A, sarr, Bfrag, Ext, yp, rsp, ssp, wsp);
  hipLaunchKernelGGL(finish_kernel, dim3(2048), dim3(256), 0, stream,
                     x2, sqarr, yp, rsp, ssp, wsp, Wg, bg, W2, b2, out, l1c, l2c);
  hipLaunchKernelGGL(loss_kernel, dim3(1), dim3(256), 0, stream, l1c, l2c, out);
}